// Round 1
// baseline (7563.203 us; speedup 1.0000x reference)
//
#include <hip/hip_runtime.h>
#include <hip/hip_fp8.h>

// CausalConv3dFP8: x (2,128,4,192,320) f32, w (128,128,3,3,3) f32.
// Both fp8-e4m3 round-tripped, conv pads: temporal (2,0) causal, spatial (1,1).
// Round 1: correct register-tiled vector-FMA baseline (MFMA comes next round).

namespace {
constexpr int Bn = 2, Cc = 128, Dd = 4, Hh = 192, Ww = 320;
constexpr int TH = 4, TW = 32;     // output tile per block (per (b,d))
constexpr int CI = 8;              // cin chunk staged in LDS
constexpr int NTAP = 27;
constexpr int LROW = 36;           // padded LDS row in floats (34 used, 16B-aligned rows)
constexpr int LDS_X = 3 * CI * 6 * LROW;  // kd-depths x cin x rows x row = 5184 floats
}

__device__ __forceinline__ float qdq(float v) {
  __hip_fp8_e4m3 q(v);           // OCP e4m3fn on gfx950, RNE — matches ml_dtypes
  return static_cast<float>(q);
}

__global__ void prep_w_kernel(const float* __restrict__ w, float* __restrict__ w2) {
  int idx = blockIdx.x * 256 + threadIdx.x;
  if (idx >= Cc * Cc * NTAP) return;
  // source layout (co, ci, kd, kh, kw) -> dest [tap][ci][co]
  int tap = idx % NTAP;
  int t = idx / NTAP;
  int ci = t % Cc;
  int co = t / Cc;
  w2[(tap * Cc + ci) * Cc + co] = qdq(w[idx]);
}

__global__ __launch_bounds__(256) void conv_kernel(
    const float* __restrict__ x, const float* __restrict__ w2,
    float* __restrict__ out) {
  __shared__ float lx[LDS_X];
  const int tid = threadIdx.x;
  const int b = blockIdx.z >> 2;
  const int dout = blockIdx.z & 3;
  const int h0 = blockIdx.y * TH;
  const int w0 = blockIdx.x * TW;
  // thread -> (cout group of 8) x (hh, 8-wide w group)
  const int cog = tid >> 4;        // 0..15
  const int sp = tid & 15;
  const int hh = sp >> 2;          // 0..3
  const int wg = sp & 3;           // 0..3
  const int co0 = cog * 8;

  float acc[8][8];
  #pragma unroll
  for (int i = 0; i < 8; ++i)
    #pragma unroll
    for (int j = 0; j < 8; ++j) acc[i][j] = 0.f;

  for (int cc = 0; cc < Cc / CI; ++cc) {
    __syncthreads();
    // ---- stage x chunk into LDS (fp8 round-trip applied here) ----
    for (int i = tid; i < LDS_X; i += 256) {
      int wi = i % LROW;                 // 0..35 (0 == out w0-1)
      int r = (i / LROW) % 6;            // 0..5 (0 == out h0-1)
      int ci = (i / (LROW * 6)) % CI;
      int kd = i / (LROW * 6 * CI);      // 0..2
      int din = dout - 2 + kd;
      int hi = h0 + r - 1;
      int wiG = w0 + wi - 1;
      float v = 0.f;
      if (din >= 0 && (unsigned)hi < (unsigned)Hh && (unsigned)wiG < (unsigned)Ww && wi < 34) {
        int cig = cc * CI + ci;
        v = qdq(x[(((size_t)(b * Cc + cig) * Dd + din) * Hh + hi) * Ww + wiG]);
      }
      lx[i] = v;
    }
    __syncthreads();

    // ---- compute ----
    for (int ci = 0; ci < CI; ++ci) {
      const int cig = cc * CI + ci;
      #pragma unroll
      for (int kd = 0; kd < 3; ++kd) {
        #pragma unroll
        for (int kh = 0; kh < 3; ++kh) {
          const float* xrow = &lx[((kd * CI + ci) * 6 + hh + kh) * LROW + wg * 8];
          float4 xa = *(const float4*)(xrow);
          float4 xb = *(const float4*)(xrow + 4);
          float4 xc = *(const float4*)(xrow + 8);
          float xr[12] = {xa.x, xa.y, xa.z, xa.w, xb.x, xb.y, xb.z, xb.w,
                          xc.x, xc.y, xc.z, xc.w};
          #pragma unroll
          for (int kw = 0; kw < 3; ++kw) {
            const float* wp = &w2[(size_t)(((kd * 3 + kh) * 3 + kw) * Cc + cig) * Cc + co0];
            float4 wa = *(const float4*)(wp);
            float4 wb = *(const float4*)(wp + 4);
            float wv[8] = {wa.x, wa.y, wa.z, wa.w, wb.x, wb.y, wb.z, wb.w};
            #pragma unroll
            for (int co = 0; co < 8; ++co)
              #pragma unroll
              for (int j = 0; j < 8; ++j)
                acc[co][j] = fmaf(wv[co], xr[j + kw], acc[co][j]);
          }
        }
      }
    }
  }

  // ---- epilogue ----
  const int hO = h0 + hh;
  const int wO = w0 + wg * 8;
  #pragma unroll
  for (int co = 0; co < 8; ++co) {
    float* op = &out[(((size_t)(b * Cc + co0 + co) * Dd + dout) * Hh + hO) * Ww + wO];
    *(float4*)(op) = make_float4(acc[co][0], acc[co][1], acc[co][2], acc[co][3]);
    *(float4*)(op + 4) = make_float4(acc[co][4], acc[co][5], acc[co][6], acc[co][7]);
  }
}

extern "C" void kernel_launch(void* const* d_in, const int* in_sizes, int n_in,
                              void* d_out, int out_size, void* d_ws, size_t ws_size,
                              hipStream_t stream) {
  const float* x = (const float*)d_in[0];
  const float* w = (const float*)d_in[1];
  float* w2 = (float*)d_ws;          // 27*128*128 f32 = 1.77 MB
  float* out = (float*)d_out;

  int nw = Cc * Cc * NTAP;
  prep_w_kernel<<<(nw + 255) / 256, 256, 0, stream>>>(w, w2);

  dim3 grid(Ww / TW, Hh / TH, Bn * Dd);   // 10 x 48 x 8
  conv_kernel<<<grid, 256, 0, stream>>>(x, w2, out);
}

// Round 2
// 542.278 us; speedup vs baseline: 13.9471x; 13.9471x over previous
//
#include <hip/hip_runtime.h>
#include <hip/hip_fp8.h>

// CausalConv3dFP8 round 2: fp8 MFMA implicit GEMM.
// x (2,128,4,192,320) f32 -> fp8 e4m3 channels-last padded in ws,
// w (128,128,3,3,3) f32 -> fp8 fragment-packed in ws.
// GEMM: M=128 cout, N=spatial (64-w tiles), K=128ci*27taps, f32 accum.

using f32x4 = __attribute__((ext_vector_type(4))) float;

namespace {
constexpr int Cc = 128, Dd = 4, Hh = 192, Ww = 320;
constexpr int DP = 6, HP = 194, WP = 322;   // padded: d +2 leading, h/w +1 each side
constexpr int NTAP = 27;
constexpr size_t XQ_BYTES = (size_t)2 * DP * HP * WP * Cc;  // 95,950,848
constexpr int PITCH = 80;                    // LDS bytes per w-row (64 used + pad)
constexpr int NROW = 3 * 3 * 66;             // 594 rows (kd,kh,w)
}

__global__ __launch_bounds__(256) void qx_kernel(const float* __restrict__ x,
                                                 unsigned char* __restrict__ xq) {
  __shared__ unsigned char lt[64 * 132];     // [w][ci], pitch 132 (33 words -> conflict-free)
  const int tid = threadIdx.x;
  const int b = blockIdx.z >> 2, d = blockIdx.z & 3;
  const int h = blockIdx.y;
  const int w0 = blockIdx.x * 64;
  const int wl = tid & 63, cig = tid >> 6;   // cig 0..3
  const size_t cstr = (size_t)Dd * Hh * Ww;
  const float* xp = x + (((size_t)b * Cc * Dd + d) * Hh + h) * Ww + w0 + wl;
  #pragma unroll 4
  for (int i = 0; i < 32; ++i) {
    int ci = cig * 32 + i;
    __hip_fp8_e4m3 q(xp[ci * cstr]);         // coalesced along w (lanes)
    lt[wl * 132 + ci] = q.__x;
  }
  __syncthreads();
  unsigned int* xq32 = (unsigned int*)xq;
  const unsigned int* lt32 = (const unsigned int*)lt;
  const size_t rowb = (((size_t)b * DP + d + 2) * HP + h + 1) * WP + (w0 + 1);
  #pragma unroll
  for (int k = 0; k < 8; ++k) {
    int i = tid + k * 256;                   // dword 0..2047
    int w = i >> 5, c = i & 31;
    xq32[(rowb + w) * 32 + c] = lt32[w * 33 + c];
  }
}

__global__ void wpack_kernel(const float* __restrict__ w, unsigned char* __restrict__ wpk) {
  int idx = blockIdx.x * 256 + threadIdx.x;
  if (idx >= Cc * Cc * NTAP) return;
  // src (co, ci, tap) flat; dst [tap][ci>>3][co][ci&7]
  int tap = idx % NTAP;
  int t = idx / NTAP;
  int ci = t % Cc, co = t / Cc;
  __hip_fp8_e4m3 q(w[idx]);
  wpk[((size_t)(tap * 16 + (ci >> 3)) * Cc + co) * 8 + (ci & 7)] = q.__x;
}

__global__ __launch_bounds__(256) void conv_mfma(const unsigned char* __restrict__ xq,
                                                 const unsigned char* __restrict__ wpk,
                                                 float* __restrict__ out) {
  __shared__ unsigned char lb[NROW * PITCH]; // 47,520 B
  const int tid = threadIdx.x;
  const int lane = tid & 63, wv = tid >> 6;
  const int l15 = lane & 15, kg = lane >> 4;
  const int b = blockIdx.z >> 2, dout = blockIdx.z & 3;
  const int h = blockIdx.y;
  const int w0 = blockIdx.x * 64;

  f32x4 acc[2][4];
  #pragma unroll
  for (int i = 0; i < 2; ++i)
    #pragma unroll
    for (int j = 0; j < 4; ++j) acc[i][j] = (f32x4){0.f, 0.f, 0.f, 0.f};

  for (int cc = 0; cc < 2; ++cc) {
    __syncthreads();
    // ---- stage [3kd][3kh][66w][64ci] fp8 tile ----
    for (int i = tid; i < NROW * 4; i += 256) {
      int row = i >> 2, seg = i & 3;
      int wq = row % 66;
      int t2 = row / 66;
      int khh = t2 % 3, kdd = t2 / 3;
      size_t ga = ((((size_t)b * DP + dout + kdd) * HP + h + khh) * WP + w0 + wq) * Cc
                  + cc * 64 + seg * 16;
      *(uint4*)(&lb[row * PITCH + seg * 16]) = *(const uint4*)(xq + ga);
    }
    __syncthreads();
    // ---- 27 taps x 2 K-steps ----
    for (int tap = 0; tap < NTAP; ++tap) {
      const int kdd = tap / 9, khh = (tap / 3) % 3, kw = tap % 3;
      const int rowb = (kdd * 3 + khh) * 66 + kw;
      #pragma unroll
      for (int s = 0; s < 2; ++s) {
        const long* ap = (const long*)(wpk +
            ((size_t)(tap * 16 + cc * 8 + s * 4 + kg) * Cc + wv * 32 + l15) * 8);
        long a0 = ap[0];      // mf=0: co = wv*32 + l15
        long a1 = ap[16];     // mf=1: co = wv*32 + 16 + l15
        long bf[4];
        #pragma unroll
        for (int nf = 0; nf < 4; ++nf)
          bf[nf] = *(const long*)(&lb[(rowb + nf * 16 + l15) * PITCH + s * 32 + kg * 8]);
        #pragma unroll
        for (int nf = 0; nf < 4; ++nf) {
          acc[0][nf] = __builtin_amdgcn_mfma_f32_16x16x32_fp8_fp8(a0, bf[nf], acc[0][nf], 0, 0, 0);
          acc[1][nf] = __builtin_amdgcn_mfma_f32_16x16x32_fp8_fp8(a1, bf[nf], acc[1][nf], 0, 0, 0);
        }
      }
    }
  }

  // ---- epilogue: C row=(lane>>4)*4+reg -> co, col=lane&15 -> w ----
  #pragma unroll
  for (int mf = 0; mf < 2; ++mf)
    #pragma unroll
    for (int nf = 0; nf < 4; ++nf) {
      int ww = w0 + nf * 16 + l15;
      #pragma unroll
      for (int r = 0; r < 4; ++r) {
        int co = wv * 32 + mf * 16 + kg * 4 + r;
        out[(((size_t)b * Cc + co) * Dd + dout) * (size_t)(Hh * Ww) + (size_t)h * Ww + ww] =
            acc[mf][nf][r];
      }
    }
}

extern "C" void kernel_launch(void* const* d_in, const int* in_sizes, int n_in,
                              void* d_out, int out_size, void* d_ws, size_t ws_size,
                              hipStream_t stream) {
  const float* x = (const float*)d_in[0];
  const float* w = (const float*)d_in[1];
  unsigned char* xq = (unsigned char*)d_ws;                 // 95,950,848 B
  unsigned char* wpk = xq + XQ_BYTES;                       // 442,368 B
  float* out = (float*)d_out;

  hipMemsetAsync(xq, 0, XQ_BYTES, stream);                  // zero padding borders

  dim3 g1(Ww / 64, Hh, 2 * Dd);                             // 5 x 192 x 8
  qx_kernel<<<g1, 256, 0, stream>>>(x, xq);

  int nw = Cc * Cc * NTAP;
  wpack_kernel<<<(nw + 255) / 256, 256, 0, stream>>>(w, wpk);

  conv_mfma<<<g1, 256, 0, stream>>>(xq, wpk, out);
}

// Round 3
// 380.708 us; speedup vs baseline: 19.8662x; 1.4244x over previous
//
#include <hip/hip_runtime.h>
#include <hip/hip_fp8.h>

// CausalConv3dFP8 round 3: fp8 MFMA implicit GEMM, 2-h-row tile,
// conflict-free LDS banking, packed 16B A-fragments.
// xq global layout: [b][dp6][hp194][ci8 16][wp322][8B]
// wpk layout:       [tap27][ci8 16][wv4][l15 16][mf2][8B]

using f32x4 = __attribute__((ext_vector_type(4))) float;
typedef long long i64;
struct alignas(16) L2v { i64 x, y; };

namespace {
constexpr int Cc = 128, Dd = 4, Hh = 192, Ww = 320;
constexpr int DP = 6, HP = 194, WP = 322;
constexpr int NTAP = 27;
constexpr size_t PLANE = (size_t)16 * WP * 8;                 // bytes per (b,d,h) plane
constexpr size_t XQ_BYTES = (size_t)2 * DP * HP * PLANE;      // 95,950,848
}

__global__ __launch_bounds__(256) void qx_kernel(const float* __restrict__ x,
                                                 unsigned char* __restrict__ xq) {
  __shared__ unsigned char lt[64 * 132];     // [w][ci] bytes, pitch 132
  const int tid = threadIdx.x;
  const int b = blockIdx.z >> 2, d = blockIdx.z & 3;
  const int h = blockIdx.y;
  const int w0 = blockIdx.x * 64;
  const int wl = tid & 63, cig = tid >> 6;
  const size_t cstr = (size_t)Dd * Hh * Ww;
  const float* xp = x + (((size_t)b * Cc * Dd + d) * Hh + h) * Ww + w0 + wl;
  #pragma unroll 4
  for (int i = 0; i < 32; ++i) {
    int ci = cig * 32 + i;
    __hip_fp8_e4m3 q(xp[ci * cstr]);
    lt[wl * 132 + ci] = q.__x;
  }
  __syncthreads();
  unsigned char* plane = xq + ((size_t)(b * DP + d + 2) * HP + h + 1) * PLANE;
  #pragma unroll
  for (int k = 0; k < 2; ++k) {
    int i = tid + k * 256;                   // 512 uint4 total
    int g = i >> 5;                          // ci8 group 0..15
    int wp = (i & 31) * 2;                   // w pair
    i64 lo = *(const i64*)(lt + wp * 132 + g * 8);
    i64 hi = *(const i64*)(lt + (wp + 1) * 132 + g * 8);
    L2v v{lo, hi};
    *(L2v*)(plane + (size_t)g * WP * 8 + (size_t)(w0 + 1 + wp) * 8) = v;
  }
}

__global__ void wpack_kernel(const float* __restrict__ w, unsigned char* __restrict__ wpk) {
  int idx = blockIdx.x * 256 + threadIdx.x;
  if (idx >= Cc * Cc * NTAP) return;
  int tap = idx % NTAP;
  int t = idx / NTAP;
  int ci = t % Cc, co = t / Cc;
  int wv = co >> 5, mf = (co >> 4) & 1, l15 = co & 15;
  __hip_fp8_e4m3 q(w[idx]);
  wpk[((((size_t)tap * 16 + (ci >> 3)) * 4 + wv) * 16 + l15) * 16 + mf * 8 + (ci & 7)] = q.__x;
}

__global__ __launch_bounds__(256, 4) void conv_mfma(const unsigned char* __restrict__ xq,
                                                    const unsigned char* __restrict__ wpk,
                                                    float* __restrict__ out) {
  __shared__ unsigned char lb[48 * 528];     // [kd3][hrow4][g4][66w][8B] = 25,344 B
  const int tid = threadIdx.x;
  const int lane = tid & 63, wv = tid >> 6;
  const int l15 = lane & 15, kg = lane >> 4;
  const int b = blockIdx.z >> 2, dout = blockIdx.z & 3;
  const int h0 = blockIdx.y * 2;
  const int w0 = blockIdx.x * 64;

  f32x4 acc[2][2][4];                        // [hr][mf][nf]
  #pragma unroll
  for (int a = 0; a < 2; ++a)
    #pragma unroll
    for (int m = 0; m < 2; ++m)
      #pragma unroll
      for (int n = 0; n < 4; ++n) acc[a][m][n] = (f32x4){0.f, 0.f, 0.f, 0.f};

  for (int cc = 0; cc < 4; ++cc) {
    __syncthreads();
    // ---- stage 48 rows x 528B, contiguous in both global and LDS ----
    for (int i = tid; i < 48 * 33; i += 256) {
      int row = i / 33, seg = i - row * 33;
      int g = row & 3, hrow = (row >> 2) & 3, kd = row >> 4;
      const unsigned char* src = xq
          + ((size_t)(b * DP + dout + kd) * HP + h0 + hrow) * PLANE
          + (size_t)(cc * 4 + g) * WP * 8 + (size_t)w0 * 8 + seg * 16;
      *(L2v*)(lb + row * 528 + seg * 16) = *(const L2v*)src;
    }
    __syncthreads();
    // ---- 27 taps, K=32 per tap ----
    for (int tap = 0; tap < NTAP; ++tap) {
      const int kd = tap / 9, khw = tap % 9;
      const int kh = khw / 3, kw = khw % 3;
      L2v av = *(const L2v*)(wpk +
          ((((size_t)tap * 16 + cc * 4 + kg) * 4 + wv) * 16 + l15) * 16);
      #pragma unroll
      for (int hr = 0; hr < 2; ++hr) {
        const unsigned char* bbase = lb + ((kd * 4 + hr + kh) * 4 + kg) * 528 + (l15 + kw) * 8;
        #pragma unroll
        for (int nf = 0; nf < 4; ++nf) {
          i64 bf = *(const i64*)(bbase + nf * 128);
          acc[hr][0][nf] = __builtin_amdgcn_mfma_f32_16x16x32_fp8_fp8(av.x, bf, acc[hr][0][nf], 0, 0, 0);
          acc[hr][1][nf] = __builtin_amdgcn_mfma_f32_16x16x32_fp8_fp8(av.y, bf, acc[hr][1][nf], 0, 0, 0);
        }
      }
    }
  }

  // ---- epilogue: row=(kg*4+r) within mf-halves -> co, col=l15 -> w ----
  #pragma unroll
  for (int hr = 0; hr < 2; ++hr)
    #pragma unroll
    for (int mf = 0; mf < 2; ++mf)
      #pragma unroll
      for (int nf = 0; nf < 4; ++nf) {
        int ww = w0 + nf * 16 + l15;
        #pragma unroll
        for (int r = 0; r < 4; ++r) {
          int co = wv * 32 + mf * 16 + kg * 4 + r;
          out[(((size_t)b * Cc + co) * Dd + dout) * (size_t)(Hh * Ww)
              + (size_t)(h0 + hr) * Ww + ww] = acc[hr][mf][nf][r];
        }
      }
}

extern "C" void kernel_launch(void* const* d_in, const int* in_sizes, int n_in,
                              void* d_out, int out_size, void* d_ws, size_t ws_size,
                              hipStream_t stream) {
  const float* x = (const float*)d_in[0];
  const float* w = (const float*)d_in[1];
  unsigned char* xq = (unsigned char*)d_ws;
  unsigned char* wpk = xq + XQ_BYTES;        // 442,368 B
  float* out = (float*)d_out;

  hipMemsetAsync(xq, 0, XQ_BYTES, stream);   // zero pad borders

  dim3 g1(Ww / 64, Hh, 2 * Dd);              // 5 x 192 x 8
  qx_kernel<<<g1, 256, 0, stream>>>(x, xq);

  int nw = Cc * Cc * NTAP;
  wpack_kernel<<<(nw + 255) / 256, 256, 0, stream>>>(w, wpk);

  dim3 g2(Ww / 64, Hh / 2, 2 * Dd);          // 5 x 96 x 8
  conv_mfma<<<g2, 256, 0, stream>>>(xq, wpk, out);
}

// Round 4
// 284.770 us; speedup vs baseline: 26.5590x; 1.3369x over previous
//
#include <hip/hip_runtime.h>
#include <hip/hip_fp8.h>

// CausalConv3dFP8 round 4: kd-skip (causal zeros), no d-padding, border-only zeroing.
// xq global layout: [b][d4][hp194][ci8 16][wp322][8B]
// wpk layout:       [tap27][ci8 16][wv4][l15 16][mf2][8B]

using f32x4 = __attribute__((ext_vector_type(4))) float;
typedef long long i64;
struct alignas(16) L2v { i64 x, y; };

namespace {
constexpr int Cc = 128, Dd = 4, Hh = 192, Ww = 320;
constexpr int HP = 194, WP = 322;
constexpr int NTAP = 27;
constexpr size_t PLANE = (size_t)16 * WP * 8;              // 41,216 B per (b,d,h) row-plane
constexpr size_t XQ_BYTES = (size_t)2 * Dd * HP * PLANE;   // 63,967,232
constexpr int ZA = 8 * 2 * 2576;                           // h-border 16B units (PLANE/16=2576)
constexpr int ZB = 8 * 192 * 32;                           // w-border 8B units
}

__global__ __launch_bounds__(256) void zero_pad_kernel(unsigned char* __restrict__ xq) {
  int i = blockIdx.x * 256 + threadIdx.x;
  if (i < ZA) {                                    // h = 0 and h = 193 full rows
    int bd = i / (2 * 2576);
    int r = i - bd * (2 * 2576);
    int hsel = r / 2576, seg = r - hsel * 2576;
    L2v z{0, 0};
    *(L2v*)(xq + ((size_t)bd * HP + (hsel ? 193 : 0)) * PLANE + (size_t)seg * 16) = z;
  } else if (i < ZA + ZB) {                        // w = 0 and w = 321, h in 1..192
    int j = i - ZA;
    int bd = j / (192 * 32);
    int r = j - bd * (192 * 32);
    int h = r / 32 + 1;
    int t = r & 31;
    int g = t >> 1, wsel = t & 1;
    *(i64*)(xq + ((size_t)bd * HP + h) * PLANE + (size_t)g * WP * 8
            + (size_t)(wsel ? 321 : 0) * 8) = 0;
  }
}

__global__ __launch_bounds__(256) void qx_kernel(const float* __restrict__ x,
                                                 unsigned char* __restrict__ xq) {
  __shared__ unsigned char lt[64 * 132];
  const int tid = threadIdx.x;
  const int b = blockIdx.z >> 2, d = blockIdx.z & 3;
  const int h = blockIdx.y;
  const int w0 = blockIdx.x * 64;
  const int wl = tid & 63, cig = tid >> 6;
  const size_t cstr = (size_t)Dd * Hh * Ww;
  const float* xp = x + (((size_t)b * Cc * Dd + d) * Hh + h) * Ww + w0 + wl;
  #pragma unroll 4
  for (int i = 0; i < 32; ++i) {
    int ci = cig * 32 + i;
    __hip_fp8_e4m3 q(xp[ci * cstr]);
    lt[wl * 132 + ci] = q.__x;
  }
  __syncthreads();
  unsigned char* plane = xq + ((size_t)(b * Dd + d) * HP + h + 1) * PLANE;
  #pragma unroll
  for (int k = 0; k < 2; ++k) {
    int i = tid + k * 256;
    int g = i >> 5;
    int wp = (i & 31) * 2;
    i64 lo = *(const i64*)(lt + wp * 132 + g * 8);
    i64 hi = *(const i64*)(lt + (wp + 1) * 132 + g * 8);
    L2v v{lo, hi};
    *(L2v*)(plane + (size_t)g * WP * 8 + (size_t)(w0 + 1 + wp) * 8) = v;
  }
}

__global__ void wpack_kernel(const float* __restrict__ w, unsigned char* __restrict__ wpk) {
  int idx = blockIdx.x * 256 + threadIdx.x;
  if (idx >= Cc * Cc * NTAP) return;
  int tap = idx % NTAP;
  int t = idx / NTAP;
  int ci = t % Cc, co = t / Cc;
  int wv = co >> 5, mf = (co >> 4) & 1, l15 = co & 15;
  __hip_fp8_e4m3 q(w[idx]);
  wpk[((((size_t)tap * 16 + (ci >> 3)) * 4 + wv) * 16 + l15) * 16 + mf * 8 + (ci & 7)] = q.__x;
}

__global__ __launch_bounds__(256, 4) void conv_mfma(const unsigned char* __restrict__ xq,
                                                    const unsigned char* __restrict__ wpk,
                                                    float* __restrict__ out) {
  __shared__ unsigned char lb[48 * 528];           // [kd3][hrow4][g4][66w][8B]
  const int tid = threadIdx.x;
  const int lane = tid & 63, wv = tid >> 6;
  const int l15 = lane & 15, kg = lane >> 4;
  const int b = blockIdx.z >> 2, dout = blockIdx.z & 3;
  const int h0 = blockIdx.y * 2;
  const int w0 = blockIdx.x * 64;
  const int kdmin = dout >= 2 ? 0 : 2 - dout;      // causal: kd < kdmin hits zero planes

  f32x4 acc[2][2][4];
  #pragma unroll
  for (int a = 0; a < 2; ++a)
    #pragma unroll
    for (int m = 0; m < 2; ++m)
      #pragma unroll
      for (int n = 0; n < 4; ++n) acc[a][m][n] = (f32x4){0.f, 0.f, 0.f, 0.f};

  for (int cc = 0; cc < 4; ++cc) {
    __syncthreads();
    for (int i = tid + kdmin * 528; i < 48 * 33; i += 256) {
      int row = i / 33, seg = i - row * 33;
      int g = row & 3, hrow = (row >> 2) & 3, kd = row >> 4;
      const unsigned char* src = xq
          + ((size_t)(b * Dd + dout + kd - 2) * HP + h0 + hrow) * PLANE
          + (size_t)(cc * 4 + g) * WP * 8 + (size_t)w0 * 8 + seg * 16;
      *(L2v*)(lb + row * 528 + seg * 16) = *(const L2v*)src;
    }
    __syncthreads();
    for (int tap = kdmin * 9; tap < NTAP; ++tap) {
      const int kd = tap / 9, khw = tap % 9;
      const int kh = khw / 3, kw = khw % 3;
      L2v av = *(const L2v*)(wpk +
          ((((size_t)tap * 16 + cc * 4 + kg) * 4 + wv) * 16 + l15) * 16);
      #pragma unroll
      for (int hr = 0; hr < 2; ++hr) {
        const unsigned char* bbase = lb + ((kd * 4 + hr + kh) * 4 + kg) * 528 + (l15 + kw) * 8;
        #pragma unroll
        for (int nf = 0; nf < 4; ++nf) {
          i64 bf = *(const i64*)(bbase + nf * 128);
          acc[hr][0][nf] = __builtin_amdgcn_mfma_f32_16x16x32_fp8_fp8(av.x, bf, acc[hr][0][nf], 0, 0, 0);
          acc[hr][1][nf] = __builtin_amdgcn_mfma_f32_16x16x32_fp8_fp8(av.y, bf, acc[hr][1][nf], 0, 0, 0);
        }
      }
    }
  }

  #pragma unroll
  for (int hr = 0; hr < 2; ++hr)
    #pragma unroll
    for (int mf = 0; mf < 2; ++mf)
      #pragma unroll
      for (int nf = 0; nf < 4; ++nf) {
        int ww = w0 + nf * 16 + l15;
        #pragma unroll
        for (int r = 0; r < 4; ++r) {
          int co = wv * 32 + mf * 16 + kg * 4 + r;
          out[(((size_t)b * Cc + co) * Dd + dout) * (size_t)(Hh * Ww)
              + (size_t)(h0 + hr) * Ww + ww] = acc[hr][mf][nf][r];
        }
      }
}

extern "C" void kernel_launch(void* const* d_in, const int* in_sizes, int n_in,
                              void* d_out, int out_size, void* d_ws, size_t ws_size,
                              hipStream_t stream) {
  const float* x = (const float*)d_in[0];
  const float* w = (const float*)d_in[1];
  unsigned char* xq = (unsigned char*)d_ws;
  unsigned char* wpk = xq + XQ_BYTES;
  float* out = (float*)d_out;

  int nz = ZA + ZB;
  zero_pad_kernel<<<(nz + 255) / 256, 256, 0, stream>>>(xq);

  dim3 g1(Ww / 64, Hh, 2 * Dd);
  qx_kernel<<<g1, 256, 0, stream>>>(x, xq);

  int nw = Cc * Cc * NTAP;
  wpack_kernel<<<(nw + 255) / 256, 256, 0, stream>>>(w, wpk);

  dim3 g2(Ww / 64, Hh / 2, 2 * Dd);
  conv_mfma<<<g2, 256, 0, stream>>>(xq, wpk, out);
}